// Round 3
// 705.918 us; speedup vs baseline: 1.0242x; 1.0242x over previous
//
#include <hip/hip_runtime.h>
#include <hip/hip_bf16.h>
#include <math.h>

typedef __hip_bfloat16 bf16;
typedef unsigned short u16;
typedef unsigned int   u32;
typedef __bf16  bf16x8 __attribute__((ext_vector_type(8)));
typedef float   f32x4  __attribute__((ext_vector_type(4)));

#define NTOK 100352   // 32 * 56 * 56
#define QSCALE 0.17677669529663687f

// ---------------- merged fp32 -> bf16 transposes (weights, every launch) ----
__global__ __launch_bounds__(256)
void cvt_all(const float* __restrict__ qkv_w, const float* __restrict__ proj_w,
             const float* __restrict__ fc1_w, const float* __restrict__ fc2_w,
             bf16* __restrict__ wqkvT, bf16* __restrict__ wprojT,
             bf16* __restrict__ wfc1T, bf16* __restrict__ wfc2T)
{
  const int i = blockIdx.x * 256 + threadIdx.x;
  if (i < 196608) {
    const int k = i / 768, n = i % 768;
    wqkvT[n * 256 + k] = __float2bfloat16(qkv_w[i]);
  } else if (i < 262144) {
    const int j = i - 196608, k = j / 256, n = j % 256;
    wprojT[n * 256 + k] = __float2bfloat16(proj_w[j]);
  } else if (i < 524288) {
    const int j = i - 262144, k = j / 1024, n = j % 1024;
    wfc1T[n * 256 + k] = __float2bfloat16(fc1_w[j]);
  } else {
    const int j = i - 524288, k = j / 256, n = j % 256;
    wfc2T[n * 1024 + k] = __float2bfloat16(fc2_w[j]);
  }
}

// ---------------- pos-bias MLP + rel_bias table (1 block) ----------------
// rel_bias is written PADDED: [8 heads][49 rows][64 cols] (cols 49..63 = 0)
// so the attention kernel can do aligned float4 loads of 4 consecutive j.
__device__ __forceinline__ void ln16_relu(float* cur, const float* g, const float* b) {
  float mu = 0.f;
#pragma unroll
  for (int j = 0; j < 16; ++j) mu += cur[j];
  mu *= (1.f / 16.f);
  float var = 0.f;
#pragma unroll
  for (int j = 0; j < 16; ++j) { float d = cur[j] - mu; var += d * d; }
  var *= (1.f / 16.f);
  const float r = rsqrtf(var + 1e-5f);
#pragma unroll
  for (int j = 0; j < 16; ++j) {
    float y = (cur[j] - mu) * r * g[j] + b[j];
    cur[j] = fmaxf(y, 0.f);
  }
}

__global__ __launch_bounds__(256)
void pos_kernel(const float* __restrict__ ppw, const float* __restrict__ ppb,
                const float* __restrict__ g1, const float* __restrict__ lb1,
                const float* __restrict__ w1, const float* __restrict__ b1,
                const float* __restrict__ g2, const float* __restrict__ lb2,
                const float* __restrict__ w2, const float* __restrict__ b2,
                const float* __restrict__ g3, const float* __restrict__ lb3,
                const float* __restrict__ w3, const float* __restrict__ b3,
                float* __restrict__ rel_bias)
{
  __shared__ float pos_s[169 * 8];
  const int t = threadIdx.x;
  if (t < 169) {
    float cur[16], nxt[16];
    const float bh = (float)(t / 13 - 6), bw = (float)(t % 13 - 6);
#pragma unroll
    for (int j = 0; j < 16; ++j)
      cur[j] = bh * ppw[j] + bw * ppw[16 + j] + ppb[j];
    ln16_relu(cur, g1, lb1);
    for (int j = 0; j < 16; ++j) nxt[j] = b1[j];
    for (int k = 0; k < 16; ++k) { float a = cur[k]; for (int j = 0; j < 16; ++j) nxt[j] += a * w1[k * 16 + j]; }
    for (int j = 0; j < 16; ++j) cur[j] = nxt[j];
    ln16_relu(cur, g2, lb2);
    for (int j = 0; j < 16; ++j) nxt[j] = b2[j];
    for (int k = 0; k < 16; ++k) { float a = cur[k]; for (int j = 0; j < 16; ++j) nxt[j] += a * w2[k * 16 + j]; }
    for (int j = 0; j < 16; ++j) cur[j] = nxt[j];
    ln16_relu(cur, g3, lb3);
    for (int h = 0; h < 8; ++h) {
      float s = b3[h];
      for (int k = 0; k < 16; ++k) s += cur[k] * w3[k * 8 + h];
      pos_s[t * 8 + h] = s;
    }
  }
  __syncthreads();
  // padded scatter: [h][i][j] with row stride 64, zero-filled pad
  for (int e = t; e < 8 * 49 * 64; e += 256) {
    const int h = e / 3136, ij = e % 3136, i = ij / 64, j = ij % 64;
    float val = 0.f;
    if (j < 49) {
      const int dh = i / 7 - j / 7 + 6, dw = i % 7 - j % 7 + 6;
      val = pos_s[(dh * 13 + dw) * 8 + h];
    }
    rel_bias[e] = val;
  }
}

// ---------------- LayerNorm over C=256: one wave per token ----------------
__global__ __launch_bounds__(256)
void ln_wave(const float* __restrict__ xin,
             const float* __restrict__ g, const float* __restrict__ b,
             bf16* __restrict__ out)
{
  const int tok = blockIdx.x * 4 + (threadIdx.x >> 6);
  const int lane = threadIdx.x & 63;
  const float4 xv = *reinterpret_cast<const float4*>(xin + (size_t)tok * 256 + lane * 4);
  float s = xv.x + xv.y + xv.z + xv.w;
#pragma unroll
  for (int off = 1; off < 64; off <<= 1) s += __shfl_xor(s, off, 64);
  const float mu = s * (1.f / 256.f);
  const float4 dx = make_float4(xv.x - mu, xv.y - mu, xv.z - mu, xv.w - mu);
  float v = dx.x * dx.x + dx.y * dx.y + dx.z * dx.z + dx.w * dx.w;
#pragma unroll
  for (int off = 1; off < 64; off <<= 1) v += __shfl_xor(v, off, 64);
  const float rstd = rsqrtf(v * (1.f / 256.f) + 1e-5f);
  const float4 gv = *reinterpret_cast<const float4*>(g + lane * 4);
  const float4 bv = *reinterpret_cast<const float4*>(b + lane * 4);
  bf16 o0 = __float2bfloat16(dx.x * rstd * gv.x + bv.x);
  bf16 o1 = __float2bfloat16(dx.y * rstd * gv.y + bv.y);
  bf16 o2 = __float2bfloat16(dx.z * rstd * gv.z + bv.z);
  bf16 o3 = __float2bfloat16(dx.w * rstd * gv.w + bv.w);
  ushort4 st = make_ushort4(*(u16*)&o0, *(u16*)&o1, *(u16*)&o2, *(u16*)&o3);
  *reinterpret_cast<ushort4*>(out + (size_t)tok * 256 + lane * 4) = st;
}

// ---------------- MFMA GEMM: C[M,N] = A[M,K] @ BT[N,K]^T + epilogue ------
// grid: x = N-tiles (small), y = M-tiles (large) so that consecutive blocks
// share the same A panel (concurrent L2 reuse; A no longer re-swept N/128x).
template<int EPI>
__global__ __launch_bounds__(256, 2)
void gemm_mfma(const bf16* __restrict__ A, const bf16* __restrict__ BT,
               const float* __restrict__ bias, const float* __restrict__ resF,
               float* __restrict__ outF, bf16* __restrict__ outB,
               bf16* __restrict__ outQ, bf16* __restrict__ outK, bf16* __restrict__ outV,
               const int M, const int N, const int K)
{
  __shared__ __align__(16) u16 Alds[128 * 32];
  __shared__ __align__(16) u16 Blds[128 * 32];
  const int t = threadIdx.x;
  const int m0 = blockIdx.y << 7, n0 = blockIdx.x << 7;
  const int wave = t >> 6, lane = t & 63;
  const int quad = lane >> 4, l15 = lane & 15;
  const int mw = (wave & 1) << 6, nw = (wave >> 1) << 6;

  const int sr = t >> 2, sc = (t & 3) << 3;
  const bf16* ag0 = A  + (size_t)(m0 + sr) * K + sc;
  const bf16* ag1 = ag0 + (size_t)64 * K;
  const bf16* bg0 = BT + (size_t)(n0 + sr) * K + sc;
  const bf16* bg1 = bg0 + (size_t)64 * K;
  char* alds0 = (char*)Alds + t * 16;
  char* alds1 = (char*)Alds + 4096 + t * 16;
  char* blds0 = (char*)Blds + t * 16;
  char* blds1 = (char*)Blds + 4096 + t * 16;

  f32x4 acc[4][4];
#pragma unroll
  for (int mi = 0; mi < 4; ++mi)
#pragma unroll
    for (int ni = 0; ni < 4; ++ni) acc[mi][ni] = (f32x4){0.f, 0.f, 0.f, 0.f};

  for (int kt = 0; kt < K; kt += 32) {
    __builtin_amdgcn_global_load_lds((const __attribute__((address_space(1))) void*)(ag0 + kt),
        (__attribute__((address_space(3))) void*)alds0, 16, 0, 0);
    __builtin_amdgcn_global_load_lds((const __attribute__((address_space(1))) void*)(ag1 + kt),
        (__attribute__((address_space(3))) void*)alds1, 16, 0, 0);
    __builtin_amdgcn_global_load_lds((const __attribute__((address_space(1))) void*)(bg0 + kt),
        (__attribute__((address_space(3))) void*)blds0, 16, 0, 0);
    __builtin_amdgcn_global_load_lds((const __attribute__((address_space(1))) void*)(bg1 + kt),
        (__attribute__((address_space(3))) void*)blds1, 16, 0, 0);
    __syncthreads();

    bf16x8 af[4], bfr[4];
#pragma unroll
    for (int mi = 0; mi < 4; ++mi)
      af[mi] = *(const bf16x8*)(Alds + (mw + mi * 16 + l15) * 32 + quad * 8);
#pragma unroll
    for (int ni = 0; ni < 4; ++ni)
      bfr[ni] = *(const bf16x8*)(Blds + (nw + ni * 16 + l15) * 32 + quad * 8);
#pragma unroll
    for (int mi = 0; mi < 4; ++mi)
#pragma unroll
      for (int ni = 0; ni < 4; ++ni)
        acc[mi][ni] = __builtin_amdgcn_mfma_f32_16x16x32_bf16(af[mi], bfr[ni], acc[mi][ni], 0, 0, 0);
    __syncthreads();
  }

#pragma unroll
  for (int mi = 0; mi < 4; ++mi) {
#pragma unroll
    for (int r = 0; r < 4; ++r) {
      const int m = m0 + mw + mi * 16 + quad * 4 + r;
      if (EPI == 0) {
        const int bb = m / 3136, l = m % 3136;
        const int hh = l / 56, ww = l % 56;
        const int win = bb * 64 + (hh / 7) * 8 + (ww / 7);
        const int p = (hh % 7) * 7 + (ww % 7);
        const size_t tokbase = ((size_t)win * 8) * 1568 + (size_t)p * 32;
#pragma unroll
        for (int ni = 0; ni < 4; ++ni) {
          const int n = n0 + nw + ni * 16 + l15;
          const float val = acc[mi][ni][r] + bias[n];
          const int which = n >> 8, head = (n >> 5) & 7, d = n & 31;
          const size_t idx = tokbase + (size_t)head * 1568 + d;
          if (which == 0)      outQ[idx] = __float2bfloat16(val * QSCALE);
          else if (which == 1) outK[idx] = __float2bfloat16(val);
          else                 outV[idx] = __float2bfloat16(val);
        }
      } else if (EPI == 1) {
#pragma unroll
        for (int ni = 0; ni < 4; ++ni) {
          const int n = n0 + nw + ni * 16 + l15;
          outF[(size_t)m * N + n] = acc[mi][ni][r] + bias[n] + resF[(size_t)m * N + n];
        }
      } else if (EPI == 2) {
#pragma unroll
        for (int ni = 0; ni < 4; ++ni) {
          const int n = n0 + nw + ni * 16 + l15;
          const float z = acc[mi][ni][r] + bias[n];
          const float ge = 0.5f * z * (1.f + erff(z * 0.7071067811865476f));
          outB[(size_t)m * N + n] = __float2bfloat16(ge);
        }
      } else {
#pragma unroll
        for (int ni = 0; ni < 4; ++ni) {
          const int n = n0 + nw + ni * 16 + l15;
          outF[(size_t)m * N + n] = resF[(size_t)m * N + n] + acc[mi][ni][r] + bias[n];
        }
      }
    }
  }
}

// ---------------- MFMA attention v3: transposed S, 4 waves / block ---------
// Compute S^T = mfma(K, Q) so each lane owns an entire softmax column
// (16 in-register values over {mi,r}; quads combined with 2 shfl_xor).
// Softmax: 128 shuffles/lane -> 16.  P is written to a PER-WAVE LDS region
// as packed b64 (16 writes vs 64 scalar b16) and no barrier is needed.
// 256-thread blocks (4 independent (win,head) waves) for occupancy.
__global__ __launch_bounds__(256)
void attn_mfma(const bf16* __restrict__ q, const bf16* __restrict__ k,
               const bf16* __restrict__ v, const float* __restrict__ rel_bias,
               bf16* __restrict__ out)
{
  __shared__ __align__(16) u16 Ps[4][64 * 72];
  const int w = threadIdx.x >> 6;
  const int lane = threadIdx.x & 63;
  const int bid = (blockIdx.x << 2) | w;       // win*8 + head
  const int win = bid >> 3, head = bid & 7;
  const int quad = lane >> 4, l15 = lane & 15;
  const size_t base = (size_t)bid * 1568;
  u16* const myP = &Ps[w][0];

  // Q/K fragments straight from global (rows >= 49 clamped in-slice)
  bf16x8 qf[4], kf[4];
#pragma unroll
  for (int i = 0; i < 4; ++i) {
    const int rr = i * 16 + l15;
    const int rc = rr < 49 ? rr : 48;
    qf[i] = *(const bf16x8*)(q + base + rc * 32 + quad * 8);
    kf[i] = *(const bf16x8*)(k + base + rc * 32 + quad * 8);
  }

  // S^T[j][m]: j = mi*16 + quad*4 + r (K rows), m = ni*16 + l15 (Q rows)
  f32x4 St[4][4];
#pragma unroll
  for (int mi = 0; mi < 4; ++mi)
#pragma unroll
    for (int ni = 0; ni < 4; ++ni)
      St[mi][ni] = __builtin_amdgcn_mfma_f32_16x16x32_bf16(kf[mi], qf[ni],
                                                           (f32x4){0.f, 0.f, 0.f, 0.f}, 0, 0, 0);

  // V B-fragments issued now; latency hidden under the softmax VALU work.
  u16 vtmp[2][2][8];
#pragma unroll
  for (int kt = 0; kt < 2; ++kt)
#pragma unroll
    for (int jj = 0; jj < 8; ++jj) {
      const int row = kt * 32 + quad * 8 + jj;
      const int rc = row < 49 ? row : 48;
#pragma unroll
      for (int ni = 0; ni < 2; ++ni)
        vtmp[kt][ni][jj] = *(const u16*)(v + base + rc * 32 + ni * 16 + l15);
    }

  // softmax over j (in-lane across mi,r; cross-quad via 2 shuffles), then
  // pack P row m to per-wave LDS in A-operand layout [m][j], ld=72.
  const float* rb = rel_bias + head * 3136;    // padded [49][64]
#pragma unroll
  for (int ni = 0; ni < 4; ++ni) {
    const int m = ni * 16 + l15;
    const int mc = m < 49 ? m : 48;
    const float* rbp = rb + mc * 64 + quad * 4;
    float sv[4][4];
#pragma unroll
    for (int mi = 0; mi < 4; ++mi) {
      const float4 rv = *(const float4*)(rbp + mi * 16);
      const float rvx[4] = {rv.x, rv.y, rv.z, rv.w};
#pragma unroll
      for (int r = 0; r < 4; ++r) {
        const int j = mi * 16 + quad * 4 + r;
        sv[mi][r] = (j < 49) ? (St[mi][ni][r] + rvx[r]) : -3e38f;
      }
    }
    float mx0 = fmaxf(fmaxf(sv[0][0], sv[0][1]), fmaxf(sv[0][2], sv[0][3]));
    float mx1 = fmaxf(fmaxf(sv[1][0], sv[1][1]), fmaxf(sv[1][2], sv[1][3]));
    float mx2 = fmaxf(fmaxf(sv[2][0], sv[2][1]), fmaxf(sv[2][2], sv[2][3]));
    float mx3 = fmaxf(fmaxf(sv[3][0], sv[3][1]), fmaxf(sv[3][2], sv[3][3]));
    float mx = fmaxf(fmaxf(mx0, mx1), fmaxf(mx2, mx3));
    mx = fmaxf(mx, __shfl_xor(mx, 16, 64));
    mx = fmaxf(mx, __shfl_xor(mx, 32, 64));
    float sum = 0.f;
#pragma unroll
    for (int mi = 0; mi < 4; ++mi)
#pragma unroll
      for (int r = 0; r < 4; ++r) { sv[mi][r] = __expf(sv[mi][r] - mx); sum += sv[mi][r]; }
    sum += __shfl_xor(sum, 16, 64);
    sum += __shfl_xor(sum, 32, 64);
    const float inv = 1.f / sum;
#pragma unroll
    for (int mi = 0; mi < 4; ++mi) {
      bf16 p0 = __float2bfloat16(sv[mi][0] * inv);
      bf16 p1 = __float2bfloat16(sv[mi][1] * inv);
      bf16 p2 = __float2bfloat16(sv[mi][2] * inv);
      bf16 p3 = __float2bfloat16(sv[mi][3] * inv);
      const u32 a = (u32)*(u16*)&p0 | ((u32)*(u16*)&p1 << 16);
      const u32 b = (u32)*(u16*)&p2 | ((u32)*(u16*)&p3 << 16);
      *reinterpret_cast<uint2*>(myP + m * 72 + mi * 16 + quad * 4) = make_uint2(a, b);
    }
  }
  // no __syncthreads(): each wave reads only its own LDS region.

  // O = P @ V : A = P [64 x 64j], B = V^T [32d x 64j] -> O [64 x 32]
  f32x4 O[4][2];
#pragma unroll
  for (int mi = 0; mi < 4; ++mi)
#pragma unroll
    for (int ni = 0; ni < 2; ++ni) O[mi][ni] = (f32x4){0.f, 0.f, 0.f, 0.f};
#pragma unroll
  for (int kt = 0; kt < 2; ++kt) {
    bf16x8 pf[4];
#pragma unroll
    for (int mi = 0; mi < 4; ++mi)
      pf[mi] = *(const bf16x8*)(myP + (mi * 16 + l15) * 72 + kt * 32 + quad * 8);
#pragma unroll
    for (int ni = 0; ni < 2; ++ni) {
      bf16x8 vf = *(const bf16x8*)&vtmp[kt][ni][0];
#pragma unroll
      for (int mi = 0; mi < 4; ++mi)
        O[mi][ni] = __builtin_amdgcn_mfma_f32_16x16x32_bf16(pf[mi], vf, O[mi][ni], 0, 0, 0);
    }
  }

  // write out token-major [tok][256]
  const int b = win >> 6, wh = (win >> 3) & 7, wwd = win & 7;
#pragma unroll
  for (int mi = 0; mi < 4; ++mi) {
#pragma unroll
    for (int r = 0; r < 4; ++r) {
      const int m = mi * 16 + quad * 4 + r;
      if (m < 49) {
        const int r7 = m / 7, c7 = m % 7;
        const int tok = b * 3136 + (wh * 7 + r7) * 56 + (wwd * 7 + c7);
        bf16* op = out + (size_t)tok * 256 + head * 32;
#pragma unroll
        for (int ni = 0; ni < 2; ++ni)
          op[ni * 16 + l15] = __float2bfloat16(O[mi][ni][r]);
      }
    }
  }
}

// ---------------- launch ----------------
// Workspace (~207 MB):
//   [0, 128KB)   rel_bias (padded [8][49][64] f32 = 100352 B)
//   [128KB, 2MB) bf16 transposed weights
//   R1..R4 (REG = NTOK*256*2 each): R1: xn -> aout; R2,R3: q,k -> Hc (MLP
//   hidden, 2 chunks of 50176 tokens); R4: v -> yn.
//   fp32 residual xr lives in d_out itself.
extern "C" void kernel_launch(void* const* d_in, const int* in_sizes, int n_in,
                              void* d_out, int out_size, void* d_ws, size_t ws_size,
                              hipStream_t stream)
{
  const float* x      = (const float*)d_in[0];
  const float* n1g    = (const float*)d_in[1];
  const float* n1b    = (const float*)d_in[2];
  const float* qkv_w  = (const float*)d_in[3];
  const float* qkv_b  = (const float*)d_in[4];
  const float* proj_w = (const float*)d_in[5];
  const float* proj_b = (const float*)d_in[6];
  const float* pp_w   = (const float*)d_in[7];
  const float* pp_b   = (const float*)d_in[8];
  const float* p1g    = (const float*)d_in[9];
  const float* p1lb   = (const float*)d_in[10];
  const float* p1w    = (const float*)d_in[11];
  const float* p1b    = (const float*)d_in[12];
  const float* p2g    = (const float*)d_in[13];
  const float* p2lb   = (const float*)d_in[14];
  const float* p2w    = (const float*)d_in[15];
  const float* p2b    = (const float*)d_in[16];
  const float* p3g    = (const float*)d_in[17];
  const float* p3lb   = (const float*)d_in[18];
  const float* p3w    = (const float*)d_in[19];
  const float* p3b    = (const float*)d_in[20];
  const float* n2g    = (const float*)d_in[21];
  const float* n2b    = (const float*)d_in[22];
  const float* fc1_w  = (const float*)d_in[23];
  const float* fc1_b  = (const float*)d_in[24];
  const float* fc2_w  = (const float*)d_in[25];
  const float* fc2_b  = (const float*)d_in[26];

  const size_t REG = (size_t)NTOK * 256 * 2;   // 51,380,224
  char* ws = (char*)d_ws;
  float* rel_bias = (float*)ws;
  bf16* wqkvT = (bf16*)(ws + 131072);
  bf16* wprojT = wqkvT + 196608;
  bf16* wfc1T = wprojT + 65536;
  bf16* wfc2T = wfc1T + 262144;
  char* R1 = ws + (2 << 20);
  char* R2 = R1 + REG;
  char* R3 = R2 + REG;
  char* R4 = R3 + REG;

  bf16*  xn   = (bf16*)R1;        // phase 1
  bf16*  qb   = (bf16*)R2;
  bf16*  kb   = (bf16*)R3;
  bf16*  vb   = (bf16*)R4;
  bf16*  aout = (bf16*)R1;        // phase 2 (xn dead)
  float* xr   = (float*)d_out;    // fp32 residual in the output buffer
  bf16*  yn   = (bf16*)R4;        // phase 4 (v dead)
  bf16*  Hc   = (bf16*)R2;        // phase 5 (q,k dead) — spans R2+R3

  cvt_all<<<3072, 256, 0, stream>>>(qkv_w, proj_w, fc1_w, fc2_w,
                                    wqkvT, wprojT, wfc1T, wfc2T);
  pos_kernel<<<1, 256, 0, stream>>>(pp_w, pp_b, p1g, p1lb, p1w, p1b,
                                    p2g, p2lb, p2w, p2b, p3g, p3lb, p3w, p3b, rel_bias);
  ln_wave<<<NTOK / 4, 256, 0, stream>>>(x, n1g, n1b, xn);
  gemm_mfma<0><<<dim3(6, NTOK / 128), 256, 0, stream>>>(xn, wqkvT, qkv_b, nullptr,
      nullptr, nullptr, qb, kb, vb, NTOK, 768, 256);
  attn_mfma<<<4096, 256, 0, stream>>>(qb, kb, vb, rel_bias, aout);
  gemm_mfma<1><<<dim3(2, NTOK / 128), 256, 0, stream>>>(aout, wprojT, proj_b, x,
      xr, nullptr, nullptr, nullptr, nullptr, NTOK, 256, 256);
  ln_wave<<<NTOK / 4, 256, 0, stream>>>(xr, n2g, n2b, yn);

  // MLP in 2 M-chunks of 50176 tokens (hidden chunk = R2+R3):
  const int MC = 50176;
  for (int c = 0; c < 2; ++c) {
    const size_t mb = (size_t)c * MC;
    gemm_mfma<2><<<dim3(8, MC / 128), 256, 0, stream>>>(yn + mb * 256, wfc1T,
        fc1_b, nullptr, nullptr, Hc, nullptr, nullptr, nullptr, MC, 1024, 256);
    gemm_mfma<5><<<dim3(2, MC / 128), 256, 0, stream>>>(Hc, wfc2T,
        fc2_b, xr + mb * 256, xr + mb * 256, nullptr, nullptr, nullptr, nullptr,
        MC, 256, 1024);
  }
}

// Round 4
// 699.150 us; speedup vs baseline: 1.0341x; 1.0097x over previous
//
#include <hip/hip_runtime.h>
#include <hip/hip_bf16.h>
#include <math.h>

typedef __hip_bfloat16 bf16;
typedef unsigned short u16;
typedef unsigned int   u32;
typedef __bf16  bf16x8 __attribute__((ext_vector_type(8)));
typedef float   f32x4  __attribute__((ext_vector_type(4)));

#define NTOK 100352   // 32 * 56 * 56
#define QSCALE 0.17677669529663687f

// ---------------- merged fp32 -> bf16 transposes (weights, every launch) ----
__global__ __launch_bounds__(256)
void cvt_all(const float* __restrict__ qkv_w, const float* __restrict__ proj_w,
             const float* __restrict__ fc1_w, const float* __restrict__ fc2_w,
             bf16* __restrict__ wqkvT, bf16* __restrict__ wprojT,
             bf16* __restrict__ wfc1T, bf16* __restrict__ wfc2T)
{
  const int i = blockIdx.x * 256 + threadIdx.x;
  if (i < 196608) {
    const int k = i / 768, n = i % 768;
    wqkvT[n * 256 + k] = __float2bfloat16(qkv_w[i]);
  } else if (i < 262144) {
    const int j = i - 196608, k = j / 256, n = j % 256;
    wprojT[n * 256 + k] = __float2bfloat16(proj_w[j]);
  } else if (i < 524288) {
    const int j = i - 262144, k = j / 1024, n = j % 1024;
    wfc1T[n * 256 + k] = __float2bfloat16(fc1_w[j]);
  } else {
    const int j = i - 524288, k = j / 256, n = j % 256;
    wfc2T[n * 1024 + k] = __float2bfloat16(fc2_w[j]);
  }
}

// ---------------- pos-bias MLP + rel_bias table (1 block) ----------------
// rel_bias PADDED: [8 heads][49 rows][64 cols] (cols 49..63 = 0).
__device__ __forceinline__ void ln16_relu(float* cur, const float* g, const float* b) {
  float mu = 0.f;
#pragma unroll
  for (int j = 0; j < 16; ++j) mu += cur[j];
  mu *= (1.f / 16.f);
  float var = 0.f;
#pragma unroll
  for (int j = 0; j < 16; ++j) { float d = cur[j] - mu; var += d * d; }
  var *= (1.f / 16.f);
  const float r = rsqrtf(var + 1e-5f);
#pragma unroll
  for (int j = 0; j < 16; ++j) {
    float y = (cur[j] - mu) * r * g[j] + b[j];
    cur[j] = fmaxf(y, 0.f);
  }
}

__global__ __launch_bounds__(256)
void pos_kernel(const float* __restrict__ ppw, const float* __restrict__ ppb,
                const float* __restrict__ g1, const float* __restrict__ lb1,
                const float* __restrict__ w1, const float* __restrict__ b1,
                const float* __restrict__ g2, const float* __restrict__ lb2,
                const float* __restrict__ w2, const float* __restrict__ b2,
                const float* __restrict__ g3, const float* __restrict__ lb3,
                const float* __restrict__ w3, const float* __restrict__ b3,
                float* __restrict__ rel_bias)
{
  __shared__ float pos_s[169 * 8];
  const int t = threadIdx.x;
  if (t < 169) {
    float cur[16], nxt[16];
    const float bh = (float)(t / 13 - 6), bw = (float)(t % 13 - 6);
#pragma unroll
    for (int j = 0; j < 16; ++j)
      cur[j] = bh * ppw[j] + bw * ppw[16 + j] + ppb[j];
    ln16_relu(cur, g1, lb1);
    for (int j = 0; j < 16; ++j) nxt[j] = b1[j];
    for (int k = 0; k < 16; ++k) { float a = cur[k]; for (int j = 0; j < 16; ++j) nxt[j] += a * w1[k * 16 + j]; }
    for (int j = 0; j < 16; ++j) cur[j] = nxt[j];
    ln16_relu(cur, g2, lb2);
    for (int j = 0; j < 16; ++j) nxt[j] = b2[j];
    for (int k = 0; k < 16; ++k) { float a = cur[k]; for (int j = 0; j < 16; ++j) nxt[j] += a * w2[k * 16 + j]; }
    for (int j = 0; j < 16; ++j) cur[j] = nxt[j];
    ln16_relu(cur, g3, lb3);
    for (int h = 0; h < 8; ++h) {
      float s = b3[h];
      for (int k = 0; k < 16; ++k) s += cur[k] * w3[k * 8 + h];
      pos_s[t * 8 + h] = s;
    }
  }
  __syncthreads();
  for (int e = t; e < 8 * 49 * 64; e += 256) {
    const int h = e / 3136, ij = e % 3136, i = ij / 64, j = ij % 64;
    float val = 0.f;
    if (j < 49) {
      const int dh = i / 7 - j / 7 + 6, dw = i % 7 - j % 7 + 6;
      val = pos_s[(dh * 13 + dw) * 8 + h];
    }
    rel_bias[e] = val;
  }
}

// ---------------- LayerNorm over C=256: one wave per token ----------------
__global__ __launch_bounds__(256)
void ln_wave(const float* __restrict__ xin,
             const float* __restrict__ g, const float* __restrict__ b,
             bf16* __restrict__ out)
{
  const int tok = blockIdx.x * 4 + (threadIdx.x >> 6);
  const int lane = threadIdx.x & 63;
  const float4 xv = *reinterpret_cast<const float4*>(xin + (size_t)tok * 256 + lane * 4);
  float s = xv.x + xv.y + xv.z + xv.w;
#pragma unroll
  for (int off = 1; off < 64; off <<= 1) s += __shfl_xor(s, off, 64);
  const float mu = s * (1.f / 256.f);
  const float4 dx = make_float4(xv.x - mu, xv.y - mu, xv.z - mu, xv.w - mu);
  float v = dx.x * dx.x + dx.y * dx.y + dx.z * dx.z + dx.w * dx.w;
#pragma unroll
  for (int off = 1; off < 64; off <<= 1) v += __shfl_xor(v, off, 64);
  const float rstd = rsqrtf(v * (1.f / 256.f) + 1e-5f);
  const float4 gv = *reinterpret_cast<const float4*>(g + lane * 4);
  const float4 bv = *reinterpret_cast<const float4*>(b + lane * 4);
  bf16 o0 = __float2bfloat16(dx.x * rstd * gv.x + bv.x);
  bf16 o1 = __float2bfloat16(dx.y * rstd * gv.y + bv.y);
  bf16 o2 = __float2bfloat16(dx.z * rstd * gv.z + bv.z);
  bf16 o3 = __float2bfloat16(dx.w * rstd * gv.w + bv.w);
  ushort4 st = make_ushort4(*(u16*)&o0, *(u16*)&o1, *(u16*)&o2, *(u16*)&o3);
  *reinterpret_cast<ushort4*>(out + (size_t)tok * 256 + lane * 4) = st;
}

// ---------------- MFMA GEMM: C[M,N] = A[M,K] @ BT[N,K]^T + epilogue ------
// grid: x = N-tiles (small), y = M-tiles (large): consecutive blocks share
// the A panel (concurrent L2 reuse).
// LDS tiles use a both-sides XOR swizzle: 16B block index b of row r lives
// at position b ^ ((r>>1)&3).  global_load_lds dest stays LINEAR (t*16);
// the global SOURCE column is pre-swizzled per-lane; ds_read applies the
// same XOR.  8-way bank conflict -> 2-way (free).
// EPI: 0 = bias -> bf16 store (qkv, token-major)
//      1 = bias + resF -> fp32 (proj)
//      2 = bias + gelu -> bf16 (fc1)
//      3 = resF + bias -> fp32 (fc2)
template<int EPI>
__global__ __launch_bounds__(256, 2)
void gemm_mfma(const bf16* __restrict__ A, const bf16* __restrict__ BT,
               const float* __restrict__ bias, const float* __restrict__ resF,
               float* __restrict__ outF, bf16* __restrict__ outB,
               const int M, const int N, const int K)
{
  __shared__ __align__(16) u16 Alds[128 * 32];
  __shared__ __align__(16) u16 Blds[128 * 32];
  const int t = threadIdx.x;
  const int m0 = blockIdx.y << 7, n0 = blockIdx.x << 7;
  const int wave = t >> 6, lane = t & 63;
  const int quad = lane >> 4, l15 = lane & 15;
  const int mw = (wave & 1) << 6, nw = (wave >> 1) << 6;

  // staging: thread t fills LDS position (row t>>2, 16B-block t&3) linearly;
  // source column pre-swizzled so that read-side XOR finds the right block.
  const int sr = t >> 2;
  const int sc = (((t & 3) ^ ((sr >> 1) & 3)) << 3);
  const bf16* ag0 = A  + (size_t)(m0 + sr) * K + sc;
  const bf16* ag1 = ag0 + (size_t)64 * K;
  const bf16* bg0 = BT + (size_t)(n0 + sr) * K + sc;
  const bf16* bg1 = bg0 + (size_t)64 * K;
  char* alds0 = (char*)Alds + t * 16;
  char* alds1 = (char*)Alds + 4096 + t * 16;
  char* blds0 = (char*)Blds + t * 16;
  char* blds1 = (char*)Blds + 4096 + t * 16;

  // read-side swizzled block offset: rows R = base + l15, base % 16 == 0,
  // so sigma(R) = (l15>>1)&3 is constant per lane.
  const int qb8 = ((quad ^ ((l15 >> 1) & 3)) << 3);

  f32x4 acc[4][4];
#pragma unroll
  for (int mi = 0; mi < 4; ++mi)
#pragma unroll
    for (int ni = 0; ni < 4; ++ni) acc[mi][ni] = (f32x4){0.f, 0.f, 0.f, 0.f};

  for (int kt = 0; kt < K; kt += 32) {
    __builtin_amdgcn_global_load_lds((const __attribute__((address_space(1))) void*)(ag0 + kt),
        (__attribute__((address_space(3))) void*)alds0, 16, 0, 0);
    __builtin_amdgcn_global_load_lds((const __attribute__((address_space(1))) void*)(ag1 + kt),
        (__attribute__((address_space(3))) void*)alds1, 16, 0, 0);
    __builtin_amdgcn_global_load_lds((const __attribute__((address_space(1))) void*)(bg0 + kt),
        (__attribute__((address_space(3))) void*)blds0, 16, 0, 0);
    __builtin_amdgcn_global_load_lds((const __attribute__((address_space(1))) void*)(bg1 + kt),
        (__attribute__((address_space(3))) void*)blds1, 16, 0, 0);
    __syncthreads();

    bf16x8 af[4], bfr[4];
#pragma unroll
    for (int mi = 0; mi < 4; ++mi)
      af[mi] = *(const bf16x8*)(Alds + (mw + mi * 16 + l15) * 32 + qb8);
#pragma unroll
    for (int ni = 0; ni < 4; ++ni)
      bfr[ni] = *(const bf16x8*)(Blds + (nw + ni * 16 + l15) * 32 + qb8);
#pragma unroll
    for (int mi = 0; mi < 4; ++mi)
#pragma unroll
      for (int ni = 0; ni < 4; ++ni)
        acc[mi][ni] = __builtin_amdgcn_mfma_f32_16x16x32_bf16(af[mi], bfr[ni], acc[mi][ni], 0, 0, 0);
    __syncthreads();
  }

#pragma unroll
  for (int mi = 0; mi < 4; ++mi) {
#pragma unroll
    for (int r = 0; r < 4; ++r) {
      const int m = m0 + mw + mi * 16 + quad * 4 + r;
      if (EPI == 0) {
#pragma unroll
        for (int ni = 0; ni < 4; ++ni) {
          const int n = n0 + nw + ni * 16 + l15;
          outB[(size_t)m * N + n] = __float2bfloat16(acc[mi][ni][r] + bias[n]);
        }
      } else if (EPI == 1) {
#pragma unroll
        for (int ni = 0; ni < 4; ++ni) {
          const int n = n0 + nw + ni * 16 + l15;
          outF[(size_t)m * N + n] = acc[mi][ni][r] + bias[n] + resF[(size_t)m * N + n];
        }
      } else if (EPI == 2) {
#pragma unroll
        for (int ni = 0; ni < 4; ++ni) {
          const int n = n0 + nw + ni * 16 + l15;
          const float z = acc[mi][ni][r] + bias[n];
          const float ge = 0.5f * z * (1.f + erff(z * 0.7071067811865476f));
          outB[(size_t)m * N + n] = __float2bfloat16(ge);
        }
      } else {
#pragma unroll
        for (int ni = 0; ni < 4; ++ni) {
          const int n = n0 + nw + ni * 16 + l15;
          outF[(size_t)m * N + n] = resF[(size_t)m * N + n] + acc[mi][ni][r] + bias[n];
        }
      }
    }
  }
}

// ---------------- MFMA attention v4: token-major QKV, transposed S ---------
// QKV is the plain GEMM output [tok][768] (q|k|v interleaved by 256-col
// slabs, 8 heads x 32 within each).  A per-wave 64-entry LDS table maps
// window row -> token index (rows >= 49 clamped).  Q-scale folded into the
// softmax bias fma (S*QSCALE + rel_bias).  S^T = mfma(K,Q): lane owns a
// softmax column in-register; cross-quad combine = 2 shuffles.
__global__ __launch_bounds__(256)
void attn_mfma(const bf16* __restrict__ qkv, const float* __restrict__ rel_bias,
               bf16* __restrict__ out)
{
  __shared__ __align__(16) u16 Ps[4][64 * 72];
  __shared__ int toks[4][64];
  const int w = threadIdx.x >> 6;
  const int lane = threadIdx.x & 63;
  const int bid = (blockIdx.x << 2) | w;       // win*8 + head
  const int win = bid >> 3, head = bid & 7;
  const int quad = lane >> 4, l15 = lane & 15;
  const int hq = head * 32;
  u16* const myP = &Ps[w][0];

  // window row -> token table (one entry per lane)
  {
    const int b = win >> 6, wh = (win >> 3) & 7, wwd = win & 7;
    const int winbase = b * 3136 + wh * 7 * 56 + wwd * 7;
    const int rc = lane < 49 ? lane : 48;
    toks[w][lane] = winbase + (rc / 7) * 56 + (rc % 7);
  }
  __syncthreads();

  // Q/K fragments straight from global (token-major)
  bf16x8 qf[4], kf[4];
#pragma unroll
  for (int i = 0; i < 4; ++i) {
    const size_t rowb = (size_t)toks[w][i * 16 + l15] * 768 + hq + quad * 8;
    qf[i] = *(const bf16x8*)(qkv + rowb);
    kf[i] = *(const bf16x8*)(qkv + rowb + 256);
  }

  // S^T[j][m]: j = mi*16 + quad*4 + r (K rows), m = ni*16 + l15 (Q rows)
  f32x4 St[4][4];
#pragma unroll
  for (int mi = 0; mi < 4; ++mi)
#pragma unroll
    for (int ni = 0; ni < 4; ++ni)
      St[mi][ni] = __builtin_amdgcn_mfma_f32_16x16x32_bf16(kf[mi], qf[ni],
                                                           (f32x4){0.f, 0.f, 0.f, 0.f}, 0, 0, 0);

  // V B-fragments: vtmp[kt][ni][jj] = V[kt*32+quad*8+jj][ni*16+l15]
  u16 vtmp[2][2][8];
#pragma unroll
  for (int kt = 0; kt < 2; ++kt)
#pragma unroll
    for (int jj = 0; jj < 8; ++jj) {
      const size_t rowb = (size_t)toks[w][kt * 32 + quad * 8 + jj] * 768 + 512 + hq;
#pragma unroll
      for (int ni = 0; ni < 2; ++ni)
        vtmp[kt][ni][jj] = *(const u16*)(qkv + rowb + ni * 16 + l15);
    }

  // softmax over j (in-lane across mi,r; cross-quad via 2 shuffles)
  const float* rb = rel_bias + head * 3136;    // padded [49][64]
#pragma unroll
  for (int ni = 0; ni < 4; ++ni) {
    const int m = ni * 16 + l15;
    const int mc = m < 49 ? m : 48;
    const float* rbp = rb + mc * 64 + quad * 4;
    float sv[4][4];
#pragma unroll
    for (int mi = 0; mi < 4; ++mi) {
      const float4 rv = *(const float4*)(rbp + mi * 16);
      const float rvx[4] = {rv.x, rv.y, rv.z, rv.w};
#pragma unroll
      for (int r = 0; r < 4; ++r) {
        const int j = mi * 16 + quad * 4 + r;
        sv[mi][r] = (j < 49) ? fmaf(St[mi][ni][r], QSCALE, rvx[r]) : -3e38f;
      }
    }
    float mx0 = fmaxf(fmaxf(sv[0][0], sv[0][1]), fmaxf(sv[0][2], sv[0][3]));
    float mx1 = fmaxf(fmaxf(sv[1][0], sv[1][1]), fmaxf(sv[1][2], sv[1][3]));
    float mx2 = fmaxf(fmaxf(sv[2][0], sv[2][1]), fmaxf(sv[2][2], sv[2][3]));
    float mx3 = fmaxf(fmaxf(sv[3][0], sv[3][1]), fmaxf(sv[3][2], sv[3][3]));
    float mx = fmaxf(fmaxf(mx0, mx1), fmaxf(mx2, mx3));
    mx = fmaxf(mx, __shfl_xor(mx, 16, 64));
    mx = fmaxf(mx, __shfl_xor(mx, 32, 64));
    float sum = 0.f;
#pragma unroll
    for (int mi = 0; mi < 4; ++mi)
#pragma unroll
      for (int r = 0; r < 4; ++r) { sv[mi][r] = __expf(sv[mi][r] - mx); sum += sv[mi][r]; }
    sum += __shfl_xor(sum, 16, 64);
    sum += __shfl_xor(sum, 32, 64);
    const float inv = 1.f / sum;
#pragma unroll
    for (int mi = 0; mi < 4; ++mi) {
      bf16 p0 = __float2bfloat16(sv[mi][0] * inv);
      bf16 p1 = __float2bfloat16(sv[mi][1] * inv);
      bf16 p2 = __float2bfloat16(sv[mi][2] * inv);
      bf16 p3 = __float2bfloat16(sv[mi][3] * inv);
      const u32 a = (u32)*(u16*)&p0 | ((u32)*(u16*)&p1 << 16);
      const u32 b = (u32)*(u16*)&p2 | ((u32)*(u16*)&p3 << 16);
      *reinterpret_cast<uint2*>(myP + m * 72 + mi * 16 + quad * 4) = make_uint2(a, b);
    }
  }
  // no barrier: each wave reads only its own LDS region.

  // O = P @ V
  f32x4 O[4][2];
#pragma unroll
  for (int mi = 0; mi < 4; ++mi)
#pragma unroll
    for (int ni = 0; ni < 2; ++ni) O[mi][ni] = (f32x4){0.f, 0.f, 0.f, 0.f};
#pragma unroll
  for (int kt = 0; kt < 2; ++kt) {
    bf16x8 pf[4];
#pragma unroll
    for (int mi = 0; mi < 4; ++mi)
      pf[mi] = *(const bf16x8*)(myP + (mi * 16 + l15) * 72 + kt * 32 + quad * 8);
#pragma unroll
    for (int ni = 0; ni < 2; ++ni) {
      bf16x8 vf = *(const bf16x8*)&vtmp[kt][ni][0];
#pragma unroll
      for (int mi = 0; mi < 4; ++mi)
        O[mi][ni] = __builtin_amdgcn_mfma_f32_16x16x32_bf16(pf[mi], vf, O[mi][ni], 0, 0, 0);
    }
  }

  // write out token-major [tok][256]
#pragma unroll
  for (int mi = 0; mi < 4; ++mi) {
#pragma unroll
    for (int r = 0; r < 4; ++r) {
      const int m = mi * 16 + quad * 4 + r;
      if (m < 49) {
        bf16* op = out + (size_t)toks[w][m] * 256 + hq;
#pragma unroll
        for (int ni = 0; ni < 2; ++ni)
          op[ni * 16 + l15] = __float2bfloat16(O[mi][ni][r]);
      }
    }
  }
}

// ---------------- launch ----------------
// Workspace (~207 MB):
//   [0, 128KB)   rel_bias (padded [8][49][64] f32)
//   [128KB, 2MB) bf16 transposed weights
//   R1..R4 (REG = NTOK*256*2 each): R1: xn -> aout; R2..R4: qkv (token-major
//   [tok][768], 3*REG) -> Hc (MLP hidden chunks, R2+R3) ; R4: yn after attn.
//   fp32 residual xr lives in d_out itself.
extern "C" void kernel_launch(void* const* d_in, const int* in_sizes, int n_in,
                              void* d_out, int out_size, void* d_ws, size_t ws_size,
                              hipStream_t stream)
{
  const float* x      = (const float*)d_in[0];
  const float* n1g    = (const float*)d_in[1];
  const float* n1b    = (const float*)d_in[2];
  const float* qkv_w  = (const float*)d_in[3];
  const float* qkv_b  = (const float*)d_in[4];
  const float* proj_w = (const float*)d_in[5];
  const float* proj_b = (const float*)d_in[6];
  const float* pp_w   = (const float*)d_in[7];
  const float* pp_b   = (const float*)d_in[8];
  const float* p1g    = (const float*)d_in[9];
  const float* p1lb   = (const float*)d_in[10];
  const float* p1w    = (const float*)d_in[11];
  const float* p1b    = (const float*)d_in[12];
  const float* p2g    = (const float*)d_in[13];
  const float* p2lb   = (const float*)d_in[14];
  const float* p2w    = (const float*)d_in[15];
  const float* p2b    = (const float*)d_in[16];
  const float* p3g    = (const float*)d_in[17];
  const float* p3lb   = (const float*)d_in[18];
  const float* p3w    = (const float*)d_in[19];
  const float* p3b    = (const float*)d_in[20];
  const float* n2g    = (const float*)d_in[21];
  const float* n2b    = (const float*)d_in[22];
  const float* fc1_w  = (const float*)d_in[23];
  const float* fc1_b  = (const float*)d_in[24];
  const float* fc2_w  = (const float*)d_in[25];
  const float* fc2_b  = (const float*)d_in[26];

  const size_t REG = (size_t)NTOK * 256 * 2;   // 51,380,224
  char* ws = (char*)d_ws;
  float* rel_bias = (float*)ws;
  bf16* wqkvT = (bf16*)(ws + 131072);
  bf16* wprojT = wqkvT + 196608;
  bf16* wfc1T = wprojT + 65536;
  bf16* wfc2T = wfc1T + 262144;
  char* R1 = ws + (2 << 20);
  char* R2 = R1 + REG;
  char* R3 = R2 + REG;
  char* R4 = R3 + REG;

  bf16*  xn   = (bf16*)R1;        // phase 1
  bf16*  qkvb = (bf16*)R2;        // token-major [NTOK][768], spans R2..R4
  bf16*  aout = (bf16*)R1;        // phase 2 (xn dead)
  float* xr   = (float*)d_out;    // fp32 residual in the output buffer
  bf16*  yn   = (bf16*)R4;        // phase 4 (qkv dead)
  bf16*  Hc   = (bf16*)R2;        // phase 5 — spans R2+R3

  cvt_all<<<3072, 256, 0, stream>>>(qkv_w, proj_w, fc1_w, fc2_w,
                                    wqkvT, wprojT, wfc1T, wfc2T);
  pos_kernel<<<1, 256, 0, stream>>>(pp_w, pp_b, p1g, p1lb, p1w, p1b,
                                    p2g, p2lb, p2w, p2b, p3g, p3lb, p3w, p3b, rel_bias);
  ln_wave<<<NTOK / 4, 256, 0, stream>>>(x, n1g, n1b, xn);
  gemm_mfma<0><<<dim3(6, NTOK / 128), 256, 0, stream>>>(xn, wqkvT, qkv_b, nullptr,
      nullptr, qkvb, NTOK, 768, 256);
  attn_mfma<<<4096, 256, 0, stream>>>(qkvb, rel_bias, aout);
  gemm_mfma<1><<<dim3(2, NTOK / 128), 256, 0, stream>>>(aout, wprojT, proj_b, x,
      xr, nullptr, NTOK, 256, 256);
  ln_wave<<<NTOK / 4, 256, 0, stream>>>(xr, n2g, n2b, yn);

  // MLP in 2 M-chunks of 50176 tokens (hidden chunk = R2+R3):
  const int MC = 50176;
  for (int c = 0; c < 2; ++c) {
    const size_t mb = (size_t)c * MC;
    gemm_mfma<2><<<dim3(8, MC / 128), 256, 0, stream>>>(yn + mb * 256, wfc1T,
        fc1_b, nullptr, nullptr, Hc, MC, 1024, 256);
    gemm_mfma<3><<<dim3(2, MC / 128), 256, 0, stream>>>(Hc, wfc2T,
        fc2_b, xr + mb * 256, xr + mb * 256, nullptr, MC, 256, 1024);
  }
}

// Round 5
// 650.706 us; speedup vs baseline: 1.1111x; 1.0744x over previous
//
#include <hip/hip_runtime.h>
#include <hip/hip_bf16.h>
#include <math.h>

typedef __hip_bfloat16 bf16;
typedef unsigned short u16;
typedef unsigned int   u32;
typedef __bf16  bf16x8 __attribute__((ext_vector_type(8)));
typedef float   f32x4  __attribute__((ext_vector_type(4)));

#define NTOK 100352   // 32 * 56 * 56
#define QSCALE 0.17677669529663687f

// ---------------- merged fp32 -> bf16 transposes (weights, every launch) ----
__global__ __launch_bounds__(256)
void cvt_all(const float* __restrict__ qkv_w, const float* __restrict__ proj_w,
             const float* __restrict__ fc1_w, const float* __restrict__ fc2_w,
             bf16* __restrict__ wqkvT, bf16* __restrict__ wprojT,
             bf16* __restrict__ wfc1T, bf16* __restrict__ wfc2T)
{
  const int i = blockIdx.x * 256 + threadIdx.x;
  if (i < 196608) {
    const int k = i / 768, n = i % 768;
    wqkvT[n * 256 + k] = __float2bfloat16(qkv_w[i]);
  } else if (i < 262144) {
    const int j = i - 196608, k = j / 256, n = j % 256;
    wprojT[n * 256 + k] = __float2bfloat16(proj_w[j]);
  } else if (i < 524288) {
    const int j = i - 262144, k = j / 1024, n = j % 1024;
    wfc1T[n * 256 + k] = __float2bfloat16(fc1_w[j]);
  } else {
    const int j = i - 524288, k = j / 256, n = j % 256;
    wfc2T[n * 1024 + k] = __float2bfloat16(fc2_w[j]);
  }
}

// ---------------- pos-bias MLP + rel_bias table (1 block) ----------------
// rel_bias PADDED: [8 heads][49 rows][64 cols] (cols 49..63 = 0).
__device__ __forceinline__ void ln16_relu(float* cur, const float* g, const float* b) {
  float mu = 0.f;
#pragma unroll
  for (int j = 0; j < 16; ++j) mu += cur[j];
  mu *= (1.f / 16.f);
  float var = 0.f;
#pragma unroll
  for (int j = 0; j < 16; ++j) { float d = cur[j] - mu; var += d * d; }
  var *= (1.f / 16.f);
  const float r = rsqrtf(var + 1e-5f);
#pragma unroll
  for (int j = 0; j < 16; ++j) {
    float y = (cur[j] - mu) * r * g[j] + b[j];
    cur[j] = fmaxf(y, 0.f);
  }
}

__global__ __launch_bounds__(256)
void pos_kernel(const float* __restrict__ ppw, const float* __restrict__ ppb,
                const float* __restrict__ g1, const float* __restrict__ lb1,
                const float* __restrict__ w1, const float* __restrict__ b1,
                const float* __restrict__ g2, const float* __restrict__ lb2,
                const float* __restrict__ w2, const float* __restrict__ b2,
                const float* __restrict__ g3, const float* __restrict__ lb3,
                const float* __restrict__ w3, const float* __restrict__ b3,
                float* __restrict__ rel_bias)
{
  __shared__ float pos_s[169 * 8];
  const int t = threadIdx.x;
  if (t < 169) {
    float cur[16], nxt[16];
    const float bh = (float)(t / 13 - 6), bw = (float)(t % 13 - 6);
#pragma unroll
    for (int j = 0; j < 16; ++j)
      cur[j] = bh * ppw[j] + bw * ppw[16 + j] + ppb[j];
    ln16_relu(cur, g1, lb1);
    for (int j = 0; j < 16; ++j) nxt[j] = b1[j];
    for (int k = 0; k < 16; ++k) { float a = cur[k]; for (int j = 0; j < 16; ++j) nxt[j] += a * w1[k * 16 + j]; }
    for (int j = 0; j < 16; ++j) cur[j] = nxt[j];
    ln16_relu(cur, g2, lb2);
    for (int j = 0; j < 16; ++j) nxt[j] = b2[j];
    for (int k = 0; k < 16; ++k) { float a = cur[k]; for (int j = 0; j < 16; ++j) nxt[j] += a * w2[k * 16 + j]; }
    for (int j = 0; j < 16; ++j) cur[j] = nxt[j];
    ln16_relu(cur, g3, lb3);
    for (int h = 0; h < 8; ++h) {
      float s = b3[h];
      for (int k = 0; k < 16; ++k) s += cur[k] * w3[k * 8 + h];
      pos_s[t * 8 + h] = s;
    }
  }
  __syncthreads();
  for (int e = t; e < 8 * 49 * 64; e += 256) {
    const int h = e / 3136, ij = e % 3136, i = ij / 64, j = ij % 64;
    float val = 0.f;
    if (j < 49) {
      const int dh = i / 7 - j / 7 + 6, dw = i % 7 - j % 7 + 6;
      val = pos_s[(dh * 13 + dw) * 8 + h];
    }
    rel_bias[e] = val;
  }
}

// ---------------- LayerNorm over C=256: one wave per token ----------------
__global__ __launch_bounds__(256)
void ln_wave(const float* __restrict__ xin,
             const float* __restrict__ g, const float* __restrict__ b,
             bf16* __restrict__ out)
{
  const int tok = blockIdx.x * 4 + (threadIdx.x >> 6);
  const int lane = threadIdx.x & 63;
  const float4 xv = *reinterpret_cast<const float4*>(xin + (size_t)tok * 256 + lane * 4);
  float s = xv.x + xv.y + xv.z + xv.w;
#pragma unroll
  for (int off = 1; off < 64; off <<= 1) s += __shfl_xor(s, off, 64);
  const float mu = s * (1.f / 256.f);
  const float4 dx = make_float4(xv.x - mu, xv.y - mu, xv.z - mu, xv.w - mu);
  float v = dx.x * dx.x + dx.y * dx.y + dx.z * dx.z + dx.w * dx.w;
#pragma unroll
  for (int off = 1; off < 64; off <<= 1) v += __shfl_xor(v, off, 64);
  const float rstd = rsqrtf(v * (1.f / 256.f) + 1e-5f);
  const float4 gv = *reinterpret_cast<const float4*>(g + lane * 4);
  const float4 bv = *reinterpret_cast<const float4*>(b + lane * 4);
  bf16 o0 = __float2bfloat16(dx.x * rstd * gv.x + bv.x);
  bf16 o1 = __float2bfloat16(dx.y * rstd * gv.y + bv.y);
  bf16 o2 = __float2bfloat16(dx.z * rstd * gv.z + bv.z);
  bf16 o3 = __float2bfloat16(dx.w * rstd * gv.w + bv.w);
  ushort4 st = make_ushort4(*(u16*)&o0, *(u16*)&o1, *(u16*)&o2, *(u16*)&o3);
  *reinterpret_cast<ushort4*>(out + (size_t)tok * 256 + lane * 4) = st;
}

// ---------------- MFMA GEMM: C[M,N] = A[M,K] @ BT[N,K]^T + epilogue ------
// BK=64 (2 barriers per 32 MFMA), 128x128 tile, 4 waves.
// XCD-aware flat-id swizzle: dispatch d -> work (d%8)*(nwg/8)+d/8 so the
// NT blocks sharing an A panel run on ONE XCD's L2 (requires nwg%8==0).
// LDS rows are 128B: 16B-block b of row r stored at b^(r&7) (both-sides
// swizzle: pre-swizzled global source column + XOR'd ds_read address);
// otherwise all l15 lanes hit one bank group (128B == 32 banks).
// EPI: 0 = bias -> bf16 (qkv token-major)   1 = bias+resF -> fp32 (proj)
//      2 = bias+gelu -> bf16 (fc1)          3 = resF+bias -> fp32 (fc2)
template<int EPI>
__global__ __launch_bounds__(256, 2)
void gemm_mfma(const bf16* __restrict__ A, const bf16* __restrict__ BT,
               const float* __restrict__ bias, const float* __restrict__ resF,
               float* __restrict__ outF, bf16* __restrict__ outB,
               const int M, const int N, const int K)
{
  __shared__ __align__(16) u16 Alds[128 * 64];
  __shared__ __align__(16) u16 Blds[128 * 64];
  const int t = threadIdx.x;

  const int nwg = gridDim.x * gridDim.y;
  int f = blockIdx.y * gridDim.x + blockIdx.x;
  f = (f & 7) * (nwg >> 3) + (f >> 3);
  const int m0 = (f / gridDim.x) << 7;
  const int n0 = (f % gridDim.x) << 7;

  const int wave = t >> 6, lane = t & 63;
  const int quad = lane >> 4, l15 = lane & 15;
  const int mw = (wave & 1) << 6, nw = (wave >> 1) << 6;

  // staging: thread t fills rows {sr, sr+32, sr+64, sr+96}, 16B-block sb,
  // linear LDS dest (p*4096 + t*16); source column pre-swizzled.
  const int sr = t >> 3;              // 0..31
  const int sb = t & 7;
  const int scol = ((sb ^ (sr & 7)) << 3);
  const bf16* ag = A  + (size_t)(m0 + sr) * K + scol;
  const bf16* bg = BT + (size_t)(n0 + sr) * K + scol;
  char* alds = (char*)Alds + t * 16;
  char* blds = (char*)Blds + t * 16;

  f32x4 acc[4][4];
#pragma unroll
  for (int mi = 0; mi < 4; ++mi)
#pragma unroll
    for (int ni = 0; ni < 4; ++ni) acc[mi][ni] = (f32x4){0.f, 0.f, 0.f, 0.f};

  const int rsw = (l15 & 7);          // row&7 for all fragment rows

  for (int kt = 0; kt < K; kt += 64) {
#pragma unroll
    for (int p = 0; p < 4; ++p) {
      __builtin_amdgcn_global_load_lds(
          (const __attribute__((address_space(1))) void*)(ag + kt + (size_t)p * (K << 5)),
          (__attribute__((address_space(3))) void*)(alds + (p << 12)), 16, 0, 0);
      __builtin_amdgcn_global_load_lds(
          (const __attribute__((address_space(1))) void*)(bg + kt + (size_t)p * (K << 5)),
          (__attribute__((address_space(3))) void*)(blds + (p << 12)), 16, 0, 0);
    }
    __syncthreads();

#pragma unroll
    for (int kk = 0; kk < 2; ++kk) {
      const int blk = ((kk * 4 + quad) ^ rsw) << 4;   // swizzled 16B block
      bf16x8 af[4], bfr[4];
#pragma unroll
      for (int mi = 0; mi < 4; ++mi)
        af[mi] = *(const bf16x8*)((const char*)Alds + (mw + mi * 16 + l15) * 128 + blk);
#pragma unroll
      for (int ni = 0; ni < 4; ++ni)
        bfr[ni] = *(const bf16x8*)((const char*)Blds + (nw + ni * 16 + l15) * 128 + blk);
#pragma unroll
      for (int mi = 0; mi < 4; ++mi)
#pragma unroll
        for (int ni = 0; ni < 4; ++ni)
          acc[mi][ni] = __builtin_amdgcn_mfma_f32_16x16x32_bf16(af[mi], bfr[ni], acc[mi][ni], 0, 0, 0);
    }
    __syncthreads();
  }

#pragma unroll
  for (int mi = 0; mi < 4; ++mi) {
#pragma unroll
    for (int r = 0; r < 4; ++r) {
      const int m = m0 + mw + mi * 16 + quad * 4 + r;
      if (EPI == 0) {
#pragma unroll
        for (int ni = 0; ni < 4; ++ni) {
          const int n = n0 + nw + ni * 16 + l15;
          outB[(size_t)m * N + n] = __float2bfloat16(acc[mi][ni][r] + bias[n]);
        }
      } else if (EPI == 1) {
#pragma unroll
        for (int ni = 0; ni < 4; ++ni) {
          const int n = n0 + nw + ni * 16 + l15;
          outF[(size_t)m * N + n] = acc[mi][ni][r] + bias[n] + resF[(size_t)m * N + n];
        }
      } else if (EPI == 2) {
#pragma unroll
        for (int ni = 0; ni < 4; ++ni) {
          const int n = n0 + nw + ni * 16 + l15;
          const float z = acc[mi][ni][r] + bias[n];
          const float ge = 0.5f * z * (1.f + erff(z * 0.7071067811865476f));
          outB[(size_t)m * N + n] = __float2bfloat16(ge);
        }
      } else {
#pragma unroll
        for (int ni = 0; ni < 4; ++ni) {
          const int n = n0 + nw + ni * 16 + l15;
          outF[(size_t)m * N + n] = resF[(size_t)m * N + n] + acc[mi][ni][r] + bias[n];
        }
      }
    }
  }
}

// ---------------- MFMA attention v4: token-major QKV, transposed S ---------
__global__ __launch_bounds__(256)
void attn_mfma(const bf16* __restrict__ qkv, const float* __restrict__ rel_bias,
               bf16* __restrict__ out)
{
  __shared__ __align__(16) u16 Ps[4][64 * 72];
  __shared__ int toks[4][64];
  const int w = threadIdx.x >> 6;
  const int lane = threadIdx.x & 63;
  const int bid = (blockIdx.x << 2) | w;       // win*8 + head
  const int win = bid >> 3, head = bid & 7;
  const int quad = lane >> 4, l15 = lane & 15;
  const int hq = head * 32;
  u16* const myP = &Ps[w][0];

  // window row -> token table (one entry per lane)
  {
    const int b = win >> 6, wh = (win >> 3) & 7, wwd = win & 7;
    const int winbase = b * 3136 + wh * 7 * 56 + wwd * 7;
    const int rc = lane < 49 ? lane : 48;
    toks[w][lane] = winbase + (rc / 7) * 56 + (rc % 7);
  }
  __syncthreads();

  // Q/K fragments straight from global (token-major)
  bf16x8 qf[4], kf[4];
#pragma unroll
  for (int i = 0; i < 4; ++i) {
    const size_t rowb = (size_t)toks[w][i * 16 + l15] * 768 + hq + quad * 8;
    qf[i] = *(const bf16x8*)(qkv + rowb);
    kf[i] = *(const bf16x8*)(qkv + rowb + 256);
  }

  // S^T[j][m]: j = mi*16 + quad*4 + r (K rows), m = ni*16 + l15 (Q rows)
  f32x4 St[4][4];
#pragma unroll
  for (int mi = 0; mi < 4; ++mi)
#pragma unroll
    for (int ni = 0; ni < 4; ++ni)
      St[mi][ni] = __builtin_amdgcn_mfma_f32_16x16x32_bf16(kf[mi], qf[ni],
                                                           (f32x4){0.f, 0.f, 0.f, 0.f}, 0, 0, 0);

  // V B-fragments
  u16 vtmp[2][2][8];
#pragma unroll
  for (int kt = 0; kt < 2; ++kt)
#pragma unroll
    for (int jj = 0; jj < 8; ++jj) {
      const size_t rowb = (size_t)toks[w][kt * 32 + quad * 8 + jj] * 768 + 512 + hq;
#pragma unroll
      for (int ni = 0; ni < 2; ++ni)
        vtmp[kt][ni][jj] = *(const u16*)(qkv + rowb + ni * 16 + l15);
    }

  // softmax over j (in-lane across mi,r; cross-quad via 2 shuffles)
  const float* rb = rel_bias + head * 3136;    // padded [49][64]
#pragma unroll
  for (int ni = 0; ni < 4; ++ni) {
    const int m = ni * 16 + l15;
    const int mc = m < 49 ? m : 48;
    const float* rbp = rb + mc * 64 + quad * 4;
    float sv[4][4];
#pragma unroll
    for (int mi = 0; mi < 4; ++mi) {
      const float4 rv = *(const float4*)(rbp + mi * 16);
      const float rvx[4] = {rv.x, rv.y, rv.z, rv.w};
#pragma unroll
      for (int r = 0; r < 4; ++r) {
        const int j = mi * 16 + quad * 4 + r;
        sv[mi][r] = (j < 49) ? fmaf(St[mi][ni][r], QSCALE, rvx[r]) : -3e38f;
      }
    }
    float mx0 = fmaxf(fmaxf(sv[0][0], sv[0][1]), fmaxf(sv[0][2], sv[0][3]));
    float mx1 = fmaxf(fmaxf(sv[1][0], sv[1][1]), fmaxf(sv[1][2], sv[1][3]));
    float mx2 = fmaxf(fmaxf(sv[2][0], sv[2][1]), fmaxf(sv[2][2], sv[2][3]));
    float mx3 = fmaxf(fmaxf(sv[3][0], sv[3][1]), fmaxf(sv[3][2], sv[3][3]));
    float mx = fmaxf(fmaxf(mx0, mx1), fmaxf(mx2, mx3));
    mx = fmaxf(mx, __shfl_xor(mx, 16, 64));
    mx = fmaxf(mx, __shfl_xor(mx, 32, 64));
    float sum = 0.f;
#pragma unroll
    for (int mi = 0; mi < 4; ++mi)
#pragma unroll
      for (int r = 0; r < 4; ++r) { sv[mi][r] = __expf(sv[mi][r] - mx); sum += sv[mi][r]; }
    sum += __shfl_xor(sum, 16, 64);
    sum += __shfl_xor(sum, 32, 64);
    const float inv = 1.f / sum;
#pragma unroll
    for (int mi = 0; mi < 4; ++mi) {
      bf16 p0 = __float2bfloat16(sv[mi][0] * inv);
      bf16 p1 = __float2bfloat16(sv[mi][1] * inv);
      bf16 p2 = __float2bfloat16(sv[mi][2] * inv);
      bf16 p3 = __float2bfloat16(sv[mi][3] * inv);
      const u32 a = (u32)*(u16*)&p0 | ((u32)*(u16*)&p1 << 16);
      const u32 b = (u32)*(u16*)&p2 | ((u32)*(u16*)&p3 << 16);
      *reinterpret_cast<uint2*>(myP + m * 72 + mi * 16 + quad * 4) = make_uint2(a, b);
    }
  }
  // no barrier: each wave reads only its own LDS region.

  // O = P @ V
  f32x4 O[4][2];
#pragma unroll
  for (int mi = 0; mi < 4; ++mi)
#pragma unroll
    for (int ni = 0; ni < 2; ++ni) O[mi][ni] = (f32x4){0.f, 0.f, 0.f, 0.f};
#pragma unroll
  for (int kt = 0; kt < 2; ++kt) {
    bf16x8 pf[4];
#pragma unroll
    for (int mi = 0; mi < 4; ++mi)
      pf[mi] = *(const bf16x8*)(myP + (mi * 16 + l15) * 72 + kt * 32 + quad * 8);
#pragma unroll
    for (int ni = 0; ni < 2; ++ni) {
      bf16x8 vf = *(const bf16x8*)&vtmp[kt][ni][0];
#pragma unroll
      for (int mi = 0; mi < 4; ++mi)
        O[mi][ni] = __builtin_amdgcn_mfma_f32_16x16x32_bf16(pf[mi], vf, O[mi][ni], 0, 0, 0);
    }
  }

  // write out token-major [tok][256]
#pragma unroll
  for (int mi = 0; mi < 4; ++mi) {
#pragma unroll
    for (int r = 0; r < 4; ++r) {
      const int m = mi * 16 + quad * 4 + r;
      if (m < 49) {
        bf16* op = out + (size_t)toks[w][m] * 256 + hq;
#pragma unroll
        for (int ni = 0; ni < 2; ++ni)
          op[ni * 16 + l15] = __float2bfloat16(O[mi][ni][r]);
      }
    }
  }
}

// ---------------- launch ----------------
// Workspace (~207 MB):
//   [0, 128KB)   rel_bias (padded [8][49][64] f32)
//   [128KB, 2MB) bf16 transposed weights
//   R1..R4 (REG = NTOK*256*2 each): R1: xn -> aout; R2..R4: qkv (token-major
//   [tok][768]) -> Hc (MLP hidden chunks, R2+R3); R4: yn after attn.
//   fp32 residual xr lives in d_out itself.
extern "C" void kernel_launch(void* const* d_in, const int* in_sizes, int n_in,
                              void* d_out, int out_size, void* d_ws, size_t ws_size,
                              hipStream_t stream)
{
  const float* x      = (const float*)d_in[0];
  const float* n1g    = (const float*)d_in[1];
  const float* n1b    = (const float*)d_in[2];
  const float* qkv_w  = (const float*)d_in[3];
  const float* qkv_b  = (const float*)d_in[4];
  const float* proj_w = (const float*)d_in[5];
  const float* proj_b = (const float*)d_in[6];
  const float* pp_w   = (const float*)d_in[7];
  const float* pp_b   = (const float*)d_in[8];
  const float* p1g    = (const float*)d_in[9];
  const float* p1lb   = (const float*)d_in[10];
  const float* p1w    = (const float*)d_in[11];
  const float* p1b    = (const float*)d_in[12];
  const float* p2g    = (const float*)d_in[13];
  const float* p2lb   = (const float*)d_in[14];
  const float* p2w    = (const float*)d_in[15];
  const float* p2b    = (const float*)d_in[16];
  const float* p3g    = (const float*)d_in[17];
  const float* p3lb   = (const float*)d_in[18];
  const float* p3w    = (const float*)d_in[19];
  const float* p3b    = (const float*)d_in[20];
  const float* n2g    = (const float*)d_in[21];
  const float* n2b    = (const float*)d_in[22];
  const float* fc1_w  = (const float*)d_in[23];
  const float* fc1_b  = (const float*)d_in[24];
  const float* fc2_w  = (const float*)d_in[25];
  const float* fc2_b  = (const float*)d_in[26];

  const size_t REG = (size_t)NTOK * 256 * 2;   // 51,380,224
  char* ws = (char*)d_ws;
  float* rel_bias = (float*)ws;
  bf16* wqkvT = (bf16*)(ws + 131072);
  bf16* wprojT = wqkvT + 196608;
  bf16* wfc1T = wprojT + 65536;
  bf16* wfc2T = wfc1T + 262144;
  char* R1 = ws + (2 << 20);
  char* R2 = R1 + REG;
  char* R3 = R2 + REG;
  char* R4 = R3 + REG;

  bf16*  xn   = (bf16*)R1;        // phase 1
  bf16*  qkvb = (bf16*)R2;        // token-major [NTOK][768], spans R2..R4
  bf16*  aout = (bf16*)R1;        // phase 2 (xn dead)
  float* xr   = (float*)d_out;    // fp32 residual in the output buffer
  bf16*  yn   = (bf16*)R4;        // phase 4 (qkv dead)
  bf16*  Hc   = (bf16*)R2;        // phase 5 — spans R2+R3

  cvt_all<<<3072, 256, 0, stream>>>(qkv_w, proj_w, fc1_w, fc2_w,
                                    wqkvT, wprojT, wfc1T, wfc2T);
  pos_kernel<<<1, 256, 0, stream>>>(pp_w, pp_b, p1g, p1lb, p1w, p1b,
                                    p2g, p2lb, p2w, p2b, p3g, p3lb, p3w, p3b, rel_bias);
  ln_wave<<<NTOK / 4, 256, 0, stream>>>(x, n1g, n1b, xn);
  gemm_mfma<0><<<dim3(6, NTOK / 128), 256, 0, stream>>>(xn, wqkvT, qkv_b, nullptr,
      nullptr, qkvb, NTOK, 768, 256);
  attn_mfma<<<4096, 256, 0, stream>>>(qkvb, rel_bias, aout);
  gemm_mfma<1><<<dim3(2, NTOK / 128), 256, 0, stream>>>(aout, wprojT, proj_b, x,
      xr, nullptr, NTOK, 256, 256);
  ln_wave<<<NTOK / 4, 256, 0, stream>>>(xr, n2g, n2b, yn);

  // MLP in 2 M-chunks of 50176 tokens (hidden chunk = R2+R3):
  const int MC = 50176;
  for (int c = 0; c < 2; ++c) {
    const size_t mb = (size_t)c * MC;
    gemm_mfma<2><<<dim3(8, MC / 128), 256, 0, stream>>>(yn + mb * 256, wfc1T,
        fc1_b, nullptr, nullptr, Hc, MC, 1024, 256);
    gemm_mfma<3><<<dim3(2, MC / 128), 256, 0, stream>>>(Hc, wfc2T,
        fc2_b, xr + mb * 256, xr + mb * 256, nullptr, MC, 256, 1024);
  }
}

// Round 7
// 644.008 us; speedup vs baseline: 1.1227x; 1.0104x over previous
//
#include <hip/hip_runtime.h>
#include <hip/hip_bf16.h>
#include <math.h>

typedef __hip_bfloat16 bf16;
typedef unsigned short u16;
typedef unsigned int   u32;
typedef __bf16  bf16x8 __attribute__((ext_vector_type(8)));
typedef float   f32x4  __attribute__((ext_vector_type(4)));

#define NTOK 100352   // 32 * 56 * 56
#define QSCALE 0.17677669529663687f

// branch-free GELU: erf via Abramowitz-Stegun 7.1.25 (|eps| <= 5e-4)
__device__ __forceinline__ float fast_gelu(float z) {
  const float t = fabsf(z) * 0.7071067811865476f;
  float p = fmaf(t, 0.078108f, 0.000972f);
  p = fmaf(t, p, 0.230389f);
  p = fmaf(t, p, 0.278393f);
  p = fmaf(t, p, 1.0f);
  p = p * p; p = p * p;                       // p^4  (p >= 1)
  const float e = 1.0f - __builtin_amdgcn_rcpf(p);   // erf(|z|/sqrt2)
  const float er = copysignf(e, z);
  return 0.5f * z * (1.0f + er);
}

// ---------------- merged fp32 -> bf16 transposes (weights, every launch) ----
__global__ __launch_bounds__(256)
void cvt_all(const float* __restrict__ qkv_w, const float* __restrict__ proj_w,
             const float* __restrict__ fc1_w, const float* __restrict__ fc2_w,
             bf16* __restrict__ wqkvT, bf16* __restrict__ wprojT,
             bf16* __restrict__ wfc1T, bf16* __restrict__ wfc2T)
{
  const int i = blockIdx.x * 256 + threadIdx.x;
  if (i < 196608) {
    const int k = i / 768, n = i % 768;
    wqkvT[n * 256 + k] = __float2bfloat16(qkv_w[i]);
  } else if (i < 262144) {
    const int j = i - 196608, k = j / 256, n = j % 256;
    wprojT[n * 256 + k] = __float2bfloat16(proj_w[j]);
  } else if (i < 524288) {
    const int j = i - 262144, k = j / 1024, n = j % 1024;
    wfc1T[n * 256 + k] = __float2bfloat16(fc1_w[j]);
  } else {
    const int j = i - 524288, k = j / 256, n = j % 256;
    wfc2T[n * 1024 + k] = __float2bfloat16(fc2_w[j]);
  }
}

// ---------------- pos-bias MLP + rel_bias table (1 block) ----------------
// rel_bias PADDED: [8 heads][49 rows][64 cols] (cols 49..63 = 0).
__device__ __forceinline__ void ln16_relu(float* cur, const float* g, const float* b) {
  float mu = 0.f;
#pragma unroll
  for (int j = 0; j < 16; ++j) mu += cur[j];
  mu *= (1.f / 16.f);
  float var = 0.f;
#pragma unroll
  for (int j = 0; j < 16; ++j) { float d = cur[j] - mu; var += d * d; }
  var *= (1.f / 16.f);
  const float r = rsqrtf(var + 1e-5f);
#pragma unroll
  for (int j = 0; j < 16; ++j) {
    float y = (cur[j] - mu) * r * g[j] + b[j];
    cur[j] = fmaxf(y, 0.f);
  }
}

__global__ __launch_bounds__(256)
void pos_kernel(const float* __restrict__ ppw, const float* __restrict__ ppb,
                const float* __restrict__ g1, const float* __restrict__ lb1,
                const float* __restrict__ w1, const float* __restrict__ b1,
                const float* __restrict__ g2, const float* __restrict__ lb2,
                const float* __restrict__ w2, const float* __restrict__ b2,
                const float* __restrict__ g3, const float* __restrict__ lb3,
                const float* __restrict__ w3, const float* __restrict__ b3,
                float* __restrict__ rel_bias)
{
  __shared__ float pos_s[169 * 8];
  const int t = threadIdx.x;
  if (t < 169) {
    float cur[16], nxt[16];
    const float bh = (float)(t / 13 - 6), bw = (float)(t % 13 - 6);
#pragma unroll
    for (int j = 0; j < 16; ++j)
      cur[j] = bh * ppw[j] + bw * ppw[16 + j] + ppb[j];
    ln16_relu(cur, g1, lb1);
    for (int j = 0; j < 16; ++j) nxt[j] = b1[j];
    for (int k = 0; k < 16; ++k) { float a = cur[k]; for (int j = 0; j < 16; ++j) nxt[j] += a * w1[k * 16 + j]; }
    for (int j = 0; j < 16; ++j) cur[j] = nxt[j];
    ln16_relu(cur, g2, lb2);
    for (int j = 0; j < 16; ++j) nxt[j] = b2[j];
    for (int k = 0; k < 16; ++k) { float a = cur[k]; for (int j = 0; j < 16; ++j) nxt[j] += a * w2[k * 16 + j]; }
    for (int j = 0; j < 16; ++j) cur[j] = nxt[j];
    ln16_relu(cur, g3, lb3);
    for (int h = 0; h < 8; ++h) {
      float s = b3[h];
      for (int k = 0; k < 16; ++k) s += cur[k] * w3[k * 8 + h];
      pos_s[t * 8 + h] = s;
    }
  }
  __syncthreads();
  for (int e = t; e < 8 * 49 * 64; e += 256) {
    const int h = e / 3136, ij = e % 3136, i = ij / 64, j = ij % 64;
    float val = 0.f;
    if (j < 49) {
      const int dh = i / 7 - j / 7 + 6, dw = i % 7 - j % 7 + 6;
      val = pos_s[(dh * 13 + dw) * 8 + h];
    }
    rel_bias[e] = val;
  }
}

// ---------------- LayerNorm over C=256: one wave per token ----------------
__global__ __launch_bounds__(256)
void ln_wave(const float* __restrict__ xin,
             const float* __restrict__ g, const float* __restrict__ b,
             bf16* __restrict__ out)
{
  const int tok = blockIdx.x * 4 + (threadIdx.x >> 6);
  const int lane = threadIdx.x & 63;
  const float4 xv = *reinterpret_cast<const float4*>(xin + (size_t)tok * 256 + lane * 4);
  float s = xv.x + xv.y + xv.z + xv.w;
#pragma unroll
  for (int off = 1; off < 64; off <<= 1) s += __shfl_xor(s, off, 64);
  const float mu = s * (1.f / 256.f);
  const float4 dx = make_float4(xv.x - mu, xv.y - mu, xv.z - mu, xv.w - mu);
  float v = dx.x * dx.x + dx.y * dx.y + dx.z * dx.z + dx.w * dx.w;
#pragma unroll
  for (int off = 1; off < 64; off <<= 1) v += __shfl_xor(v, off, 64);
  const float rstd = rsqrtf(v * (1.f / 256.f) + 1e-5f);
  const float4 gv = *reinterpret_cast<const float4*>(g + lane * 4);
  const float4 bv = *reinterpret_cast<const float4*>(b + lane * 4);
  bf16 o0 = __float2bfloat16(dx.x * rstd * gv.x + bv.x);
  bf16 o1 = __float2bfloat16(dx.y * rstd * gv.y + bv.y);
  bf16 o2 = __float2bfloat16(dx.z * rstd * gv.z + bv.z);
  bf16 o3 = __float2bfloat16(dx.w * rstd * gv.w + bv.w);
  ushort4 st = make_ushort4(*(u16*)&o0, *(u16*)&o1, *(u16*)&o2, *(u16*)&o3);
  *reinterpret_cast<ushort4*>(out + (size_t)tok * 256 + lane * 4) = st;
}

// ---------------- MFMA GEMM: C[M,N] = A[M,K] @ BT[N,K]^T + epilogue ------
// BK=64, 128x128 tile, 4 waves.  XCD-aware flat-id swizzle (nwg%8==0).
// Staging LDS rows are 128B with a both-sides XOR swizzle (block b of row r
// at b^(r&7)); linear global_load_lds dest + pre-swizzled source column.
// EPI 0 (bias->bf16) / 2 (bias+gelu->bf16): LDS-transposed epilogue — C tile
// staged to LDS [128][136] u16 (pitch 272B: 16B-aligned rows), read back
// row-major, stored as 16B dwordx4 (4 x 256B segments per wave instr).
// EPI 1 (bias+resF->fp32) / 3 (resF+bias->fp32): direct stores.
template<int EPI>
__global__ __launch_bounds__(256, 3)
void gemm_mfma(const bf16* __restrict__ A, const bf16* __restrict__ BT,
               const float* __restrict__ bias, const float* __restrict__ resF,
               float* __restrict__ outF, bf16* __restrict__ outB,
               const int M, const int N, const int K)
{
  // staging uses first 32 KB (A: [0,16K), B: [16K,32K)); bf16 epilogue
  // reuses the whole array as a [128][136] u16 tile (34816 B).
  __shared__ __align__(16) u16 LdsAll[128 * 136];
  const int t = threadIdx.x;

  const int nwg = gridDim.x * gridDim.y;
  int f = blockIdx.y * gridDim.x + blockIdx.x;
  f = (f & 7) * (nwg >> 3) + (f >> 3);
  const int m0 = (f / gridDim.x) << 7;
  const int n0 = (f % gridDim.x) << 7;

  const int wave = t >> 6, lane = t & 63;
  const int quad = lane >> 4, l15 = lane & 15;
  const int mw = (wave & 1) << 6, nw = (wave >> 1) << 6;

  // staging: thread t fills rows {sr, sr+32, sr+64, sr+96}, 16B-block sb.
  const int sr = t >> 3;              // 0..31
  const int sb = t & 7;
  const int scol = ((sb ^ (sr & 7)) << 3);
  const bf16* ag = A  + (size_t)(m0 + sr) * K + scol;
  const bf16* bg = BT + (size_t)(n0 + sr) * K + scol;
  char* alds = (char*)LdsAll + t * 16;
  char* blds = (char*)LdsAll + 16384 + t * 16;

  f32x4 acc[4][4];
#pragma unroll
  for (int mi = 0; mi < 4; ++mi)
#pragma unroll
    for (int ni = 0; ni < 4; ++ni) acc[mi][ni] = (f32x4){0.f, 0.f, 0.f, 0.f};

  const int rsw = (l15 & 7);          // row&7 for all fragment rows

  for (int kt = 0; kt < K; kt += 64) {
#pragma unroll
    for (int p = 0; p < 4; ++p) {
      __builtin_amdgcn_global_load_lds(
          (const __attribute__((address_space(1))) void*)(ag + kt + (size_t)p * (K << 5)),
          (__attribute__((address_space(3))) void*)(alds + (p << 12)), 16, 0, 0);
      __builtin_amdgcn_global_load_lds(
          (const __attribute__((address_space(1))) void*)(bg + kt + (size_t)p * (K << 5)),
          (__attribute__((address_space(3))) void*)(blds + (p << 12)), 16, 0, 0);
    }
    __syncthreads();

#pragma unroll
    for (int kk = 0; kk < 2; ++kk) {
      const int blk = ((kk * 4 + quad) ^ rsw) << 4;   // swizzled 16B block
      bf16x8 af[4], bfr[4];
#pragma unroll
      for (int mi = 0; mi < 4; ++mi)
        af[mi] = *(const bf16x8*)((const char*)LdsAll + (mw + mi * 16 + l15) * 128 + blk);
#pragma unroll
      for (int ni = 0; ni < 4; ++ni)
        bfr[ni] = *(const bf16x8*)((const char*)LdsAll + 16384 + (nw + ni * 16 + l15) * 128 + blk);
#pragma unroll
      for (int mi = 0; mi < 4; ++mi)
#pragma unroll
        for (int ni = 0; ni < 4; ++ni)
          acc[mi][ni] = __builtin_amdgcn_mfma_f32_16x16x32_bf16(af[mi], bfr[ni], acc[mi][ni], 0, 0, 0);
    }
    __syncthreads();
  }

  if (EPI == 0 || EPI == 2) {
    // bias per owned column (col = nw + ni*16 + l15, independent of mi,r)
    float bv[4];
#pragma unroll
    for (int ni = 0; ni < 4; ++ni) bv[ni] = bias[n0 + nw + ni * 16 + l15];
    // stage C tile to LDS as bf16, [128][136] u16
#pragma unroll
    for (int mi = 0; mi < 4; ++mi) {
#pragma unroll
      for (int r = 0; r < 4; ++r) {
        const int row = mw + mi * 16 + quad * 4 + r;
#pragma unroll
        for (int ni = 0; ni < 4; ++ni) {
          const int col = nw + ni * 16 + l15;
          float z = acc[mi][ni][r] + bv[ni];
          if (EPI == 2) z = fast_gelu(z);
          const bf16 o = __float2bfloat16(z);
          LdsAll[row * 136 + col] = *(const u16*)&o;
        }
      }
    }
    __syncthreads();
    // readback row-major: wave covers 4 rows x 16 chunks of 16B per pass
    const int c16 = lane & 15;
    const int r4 = lane >> 4;
#pragma unroll
    for (int pass = 0; pass < 8; ++pass) {
      const int row = pass * 16 + wave * 4 + r4;
      const uint4 vv = *(const uint4*)((const char*)LdsAll + row * 272 + c16 * 16);
      *(uint4*)(outB + (size_t)(m0 + row) * N + n0 + c16 * 8) = vv;
    }
  } else {
#pragma unroll
    for (int mi = 0; mi < 4; ++mi) {
#pragma unroll
      for (int r = 0; r < 4; ++r) {
        const int m = m0 + mw + mi * 16 + quad * 4 + r;
#pragma unroll
        for (int ni = 0; ni < 4; ++ni) {
          const int n = n0 + nw + ni * 16 + l15;
          outF[(size_t)m * N + n] = acc[mi][ni][r] + bias[n] + resF[(size_t)m * N + n];
        }
      }
    }
  }
}

// ---------------- MFMA attention v4: token-major QKV, transposed S ---------
__global__ __launch_bounds__(256)
void attn_mfma(const bf16* __restrict__ qkv, const float* __restrict__ rel_bias,
               bf16* __restrict__ out)
{
  __shared__ __align__(16) u16 Ps[4][64 * 72];
  __shared__ int toks[4][64];
  const int w = threadIdx.x >> 6;
  const int lane = threadIdx.x & 63;
  const int bid = (blockIdx.x << 2) | w;       // win*8 + head
  const int win = bid >> 3, head = bid & 7;
  const int quad = lane >> 4, l15 = lane & 15;
  const int hq = head * 32;
  u16* const myP = &Ps[w][0];

  // window row -> token table (one entry per lane)
  {
    const int b = win >> 6, wh = (win >> 3) & 7, wwd = win & 7;
    const int winbase = b * 3136 + wh * 7 * 56 + wwd * 7;
    const int rc = lane < 49 ? lane : 48;
    toks[w][lane] = winbase + (rc / 7) * 56 + (rc % 7);
  }
  __syncthreads();

  // Q/K fragments straight from global (token-major)
  bf16x8 qf[4], kf[4];
#pragma unroll
  for (int i = 0; i < 4; ++i) {
    const size_t rowb = (size_t)toks[w][i * 16 + l15] * 768 + hq + quad * 8;
    qf[i] = *(const bf16x8*)(qkv + rowb);
    kf[i] = *(const bf16x8*)(qkv + rowb + 256);
  }

  // S^T[j][m]: j = mi*16 + quad*4 + r (K rows), m = ni*16 + l15 (Q rows)
  f32x4 St[4][4];
#pragma unroll
  for (int mi = 0; mi < 4; ++mi)
#pragma unroll
    for (int ni = 0; ni < 4; ++ni)
      St[mi][ni] = __builtin_amdgcn_mfma_f32_16x16x32_bf16(kf[mi], qf[ni],
                                                           (f32x4){0.f, 0.f, 0.f, 0.f}, 0, 0, 0);

  // V B-fragments
  u16 vtmp[2][2][8];
#pragma unroll
  for (int kt = 0; kt < 2; ++kt)
#pragma unroll
    for (int jj = 0; jj < 8; ++jj) {
      const size_t rowb = (size_t)toks[w][kt * 32 + quad * 8 + jj] * 768 + 512 + hq;
#pragma unroll
      for (int ni = 0; ni < 2; ++ni)
        vtmp[kt][ni][jj] = *(const u16*)(qkv + rowb + ni * 16 + l15);
    }

  // softmax over j (in-lane across mi,r; cross-quad via 2 shuffles)
  const float* rb = rel_bias + head * 3136;    // padded [49][64]
#pragma unroll
  for (int ni = 0; ni < 4; ++ni) {
    const int m = ni * 16 + l15;
    const int mc = m < 49 ? m : 48;
    const float* rbp = rb + mc * 64 + quad * 4;
    float sv[4][4];
#pragma unroll
    for (int mi = 0; mi < 4; ++mi) {
      const float4 rv = *(const float4*)(rbp + mi * 16);
      const float rvx[4] = {rv.x, rv.y, rv.z, rv.w};
#pragma unroll
      for (int r = 0; r < 4; ++r) {
        const int j = mi * 16 + quad * 4 + r;
        sv[mi][r] = (j < 49) ? fmaf(St[mi][ni][r], QSCALE, rvx[r]) : -3e38f;
      }
    }
    float mx0 = fmaxf(fmaxf(sv[0][0], sv[0][1]), fmaxf(sv[0][2], sv[0][3]));
    float mx1 = fmaxf(fmaxf(sv[1][0], sv[1][1]), fmaxf(sv[1][2], sv[1][3]));
    float mx2 = fmaxf(fmaxf(sv[2][0], sv[2][1]), fmaxf(sv[2][2], sv[2][3]));
    float mx3 = fmaxf(fmaxf(sv[3][0], sv[3][1]), fmaxf(sv[3][2], sv[3][3]));
    float mx = fmaxf(fmaxf(mx0, mx1), fmaxf(mx2, mx3));
    mx = fmaxf(mx, __shfl_xor(mx, 16, 64));
    mx = fmaxf(mx, __shfl_xor(mx, 32, 64));
    float sum = 0.f;
#pragma unroll
    for (int mi = 0; mi < 4; ++mi)
#pragma unroll
      for (int r = 0; r < 4; ++r) { sv[mi][r] = __expf(sv[mi][r] - mx); sum += sv[mi][r]; }
    sum += __shfl_xor(sum, 16, 64);
    sum += __shfl_xor(sum, 32, 64);
    const float inv = 1.f / sum;
#pragma unroll
    for (int mi = 0; mi < 4; ++mi) {
      bf16 p0 = __float2bfloat16(sv[mi][0] * inv);
      bf16 p1 = __float2bfloat16(sv[mi][1] * inv);
      bf16 p2 = __float2bfloat16(sv[mi][2] * inv);
      bf16 p3 = __float2bfloat16(sv[mi][3] * inv);
      const u32 a = (u32)*(u16*)&p0 | ((u32)*(u16*)&p1 << 16);
      const u32 b = (u32)*(u16*)&p2 | ((u32)*(u16*)&p3 << 16);
      *reinterpret_cast<uint2*>(myP + m * 72 + mi * 16 + quad * 4) = make_uint2(a, b);
    }
  }
  // no barrier: each wave reads only its own LDS region.

  // O = P @ V
  f32x4 O[4][2];
#pragma unroll
  for (int mi = 0; mi < 4; ++mi)
#pragma unroll
    for (int ni = 0; ni < 2; ++ni) O[mi][ni] = (f32x4){0.f, 0.f, 0.f, 0.f};
#pragma unroll
  for (int kt = 0; kt < 2; ++kt) {
    bf16x8 pf[4];
#pragma unroll
    for (int mi = 0; mi < 4; ++mi)
      pf[mi] = *(const bf16x8*)(myP + (mi * 16 + l15) * 72 + kt * 32 + quad * 8);
#pragma unroll
    for (int ni = 0; ni < 2; ++ni) {
      bf16x8 vf = *(const bf16x8*)&vtmp[kt][ni][0];
#pragma unroll
      for (int mi = 0; mi < 4; ++mi)
        O[mi][ni] = __builtin_amdgcn_mfma_f32_16x16x32_bf16(pf[mi], vf, O[mi][ni], 0, 0, 0);
    }
  }

  // write out token-major [tok][256]
#pragma unroll
  for (int mi = 0; mi < 4; ++mi) {
#pragma unroll
    for (int r = 0; r < 4; ++r) {
      const int m = mi * 16 + quad * 4 + r;
      if (m < 49) {
        bf16* op = out + (size_t)toks[w][m] * 256 + hq;
#pragma unroll
        for (int ni = 0; ni < 2; ++ni)
          op[ni * 16 + l15] = __float2bfloat16(O[mi][ni][r]);
      }
    }
  }
}

// ---------------- launch ----------------
extern "C" void kernel_launch(void* const* d_in, const int* in_sizes, int n_in,
                              void* d_out, int out_size, void* d_ws, size_t ws_size,
                              hipStream_t stream)
{
  const float* x      = (const float*)d_in[0];
  const float* n1g    = (const float*)d_in[1];
  const float* n1b    = (const float*)d_in[2];
  const float* qkv_w  = (const float*)d_in[3];
  const float* qkv_b  = (const float*)d_in[4];
  const float* proj_w = (const float*)d_in[5];
  const float* proj_b = (const float*)d_in[6];
  const float* pp_w   = (const float*)d_in[7];
  const float* pp_b   = (const float*)d_in[8];
  const float* p1g    = (const float*)d_in[9];
  const float* p1lb   = (const float*)d_in[10];
  const float* p1w    = (const float*)d_in[11];
  const float* p1b    = (const float*)d_in[12];
  const float* p2g    = (const float*)d_in[13];
  const float* p2lb   = (const float*)d_in[14];
  const float* p2w    = (const float*)d_in[15];
  const float* p2b    = (const float*)d_in[16];
  const float* p3g    = (const float*)d_in[17];
  const float* p3lb   = (const float*)d_in[18];
  const float* p3w    = (const float*)d_in[19];
  const float* p3b    = (const float*)d_in[20];
  const float* n2g    = (const float*)d_in[21];
  const float* n2b    = (const float*)d_in[22];
  const float* fc1_w  = (const float*)d_in[23];
  const float* fc1_b  = (const float*)d_in[24];
  const float* fc2_w  = (const float*)d_in[25];
  const float* fc2_b  = (const float*)d_in[26];

  const size_t REG = (size_t)NTOK * 256 * 2;   // 51,380,224
  char* ws = (char*)d_ws;
  float* rel_bias = (float*)ws;
  bf16* wqkvT = (bf16*)(ws + 131072);
  bf16* wprojT = wqkvT + 196608;
  bf16* wfc1T = wprojT + 65536;
  bf16* wfc2T = wfc1T + 262144;
  char* R1 = ws + (2 << 20);
  char* R2 = R1 + REG;
  char* R3 = R2 + REG;
  char* R4 = R3 + REG;

  bf16*  xn   = (bf16*)R1;        // phase 1
  bf16*  qkvb = (bf16*)R2;        // token-major [NTOK][768], spans R2..R4
  bf16*  aout = (bf16*)R1;        // phase 2 (xn dead)
  float* xr   = (float*)d_out;    // fp32 residual in the output buffer
  bf16*  yn   = (bf16*)R4;        // phase 4 (qkv dead)
  bf16*  Hc   = (bf16*)R2;        // phase 5 — spans R2+R3

  cvt_all<<<3072, 256, 0, stream>>>(qkv_w, proj_w, fc1_w, fc2_w,
                                    wqkvT, wprojT, wfc1T, wfc2T);
  pos_kernel<<<1, 256, 0, stream>>>(pp_w, pp_b, p1g, p1lb, p1w, p1b,
                                    p2g, p2lb, p2w, p2b, p3g, p3lb, p3w, p3b, rel_bias);
  ln_wave<<<NTOK / 4, 256, 0, stream>>>(x, n1g, n1b, xn);
  gemm_mfma<0><<<dim3(6, NTOK / 128), 256, 0, stream>>>(xn, wqkvT, qkv_b, nullptr,
      nullptr, qkvb, NTOK, 768, 256);
  attn_mfma<<<4096, 256, 0, stream>>>(qkvb, rel_bias, aout);
  gemm_mfma<1><<<dim3(2, NTOK / 128), 256, 0, stream>>>(aout, wprojT, proj_b, x,
      xr, nullptr, NTOK, 256, 256);
  ln_wave<<<NTOK / 4, 256, 0, stream>>>(xr, n2g, n2b, yn);

  // MLP in 2 M-chunks of 50176 tokens (hidden chunk = R2+R3):
  const int MC = 50176;
  for (int c = 0; c < 2; ++c) {
    const size_t mb = (size_t)c * MC;
    gemm_mfma<2><<<dim3(8, MC / 128), 256, 0, stream>>>(yn + mb * 256, wfc1T,
        fc1_b, nullptr, nullptr, Hc, MC, 1024, 256);
    gemm_mfma<3><<<dim3(2, MC / 128), 256, 0, stream>>>(Hc, wfc2T,
        fc2_b, xr + mb * 256, xr + mb * 256, nullptr, MC, 256, 1024);
  }
}